// Round 1
// baseline (524.470 us; speedup 1.0000x reference)
//
#include <hip/hip_runtime.h>

// Problem dims (fixed by setup_inputs): x[4,2048,4096] f32, W[4096,4096] f32,
// lora_A[16,4096], lora_B[4096,16], sigma[16]. out[4,2048,4096] f32.
// out = x @ (W + SCALING * (B*diag(sigma_masked)) @ A)^T
#define D_DIM 4096
#define R_DIM 16
#define SCALING_F 1.0f          // 16.0/16
#define THRESH 0.01f

typedef __attribute__((ext_vector_type(8))) short short8;   // 8 bf16 = 4 VGPRs
typedef __attribute__((ext_vector_type(4))) float floatx4;  // MFMA C/D

__device__ __forceinline__ unsigned int f2bf(float f) {
  union { float f; unsigned int u; } v; v.f = f;
  unsigned int u = v.u;
  u += 0x7FFFu + ((u >> 16) & 1u);   // round-to-nearest-even
  return u >> 16;
}

// ---------------- prep 1: x fp32 -> bf16 (8 elems/thread) ----------------
__global__ __launch_bounds__(256) void convert_x_kernel(
    const float* __restrict__ x, unsigned int* __restrict__ xb, int n8) {
  int idx = blockIdx.x * 256 + threadIdx.x;
  if (idx >= n8) return;
  const float4* xp = (const float4*)x;
  float4 v0 = xp[2 * idx];
  float4 v1 = xp[2 * idx + 1];
  uint4 o;
  o.x = f2bf(v0.x) | (f2bf(v0.y) << 16);
  o.y = f2bf(v0.z) | (f2bf(v0.w) << 16);
  o.z = f2bf(v1.x) | (f2bf(v1.y) << 16);
  o.w = f2bf(v1.z) | (f2bf(v1.w) << 16);
  ((uint4*)xb)[idx] = o;
}

// ------------- prep 2: W_eff = W + (B*sigma_masked) @ A -> bf16 -------------
__global__ __launch_bounds__(256) void build_weff_kernel(
    const float* __restrict__ W, const float* __restrict__ lA,
    const float* __restrict__ lB, const float* __restrict__ sigma,
    unsigned int* __restrict__ wb) {
  __shared__ float Bs[R_DIM];
  int idx = blockIdx.x * 256 + threadIdx.x;  // quad index over 16M/4 elements
  int o  = idx >> 10;                         // row (uniform per block)
  int dq = idx & 1023;                        // which float4 within the row
  if (threadIdx.x < R_DIM) {
    float s = sigma[threadIdx.x];
    s = (fabsf(s) >= THRESH) ? s : 0.0f;
    Bs[threadIdx.x] = lB[o * R_DIM + threadIdx.x] * s * SCALING_F;
  }
  __syncthreads();
  float4 acc = ((const float4*)W)[idx];
#pragma unroll
  for (int r = 0; r < R_DIM; ++r) {
    float b = Bs[r];
    float4 a = ((const float4*)(lA + (size_t)r * D_DIM))[dq];
    acc.x += b * a.x; acc.y += b * a.y; acc.z += b * a.z; acc.w += b * a.w;
  }
  uint2 p;
  p.x = f2bf(acc.x) | (f2bf(acc.y) << 16);
  p.y = f2bf(acc.z) | (f2bf(acc.w) << 16);
  ((uint2*)wb)[idx] = p;
}

// =====================================================================
// GEMM: C[M,N] = A[M,K] * B[N,K]^T, bf16 in, f32 out.
// 256x256 tile, BK=64, 8 waves (2M x 4N), 512 threads, 128 KiB LDS.
// 8-phase pipelined schedule (T2+T3+T4+T5): raw s_barrier, counted
// s_waitcnt vmcnt(4) only at phases 4/8 — staging stays in flight
// across barriers (never drains to 0 in the main loop).
//
// LDS map (bytes): A-buf0 @0, A-buf1 @32768, B-buf0 @65536, B-buf1 @98304.
// Each tile = 256 rows x 64 bf16 = 32 KB, row stride 128 B.
// Row permutation (so quadrant retirement regions are contiguous halves):
//   A: LDS row = qm*128 + wm*64 + i   (swap bits 6<->7 of global row)
//   B: LDS row = qn*128 + wn*32 + i   (qn bit -> bit 7)
// 16B-granule XOR swizzle within each row: slot s holds kgroup s^(row&7);
// inverse swizzle applied to the GLOBAL source address (linear LDS dest,
// as global_load_lds requires), same XOR applied on ds_read.
//
// Per K-tile compute order (quadrants): c1=(0,0) c2=(0,1) c3=(1,1) c4=(1,0).
// A-frags loaded at c1/c3 (reused next phase); B-frags at c1/c2/c4.
// Steady-state frame f computes tiles 2f (buf0, P1-P4) and 2f+1 (buf1, P5-P8);
// stages: P1:A1(2f+1) P2:B0(2f+1) P3:A0(2f+2) P4:B1(2f+2)
//         P5:A1(2f+2) P6:B0(2f+2) P7:A0(2f+3) P8:B1(2f+3)
// Every staged region retired >=1 phase earlier; every consumed half is
// >=3 phases older than its vmcnt(4)+barrier. Tail stages wrap k (&8191).
// =====================================================================

__device__ __forceinline__ void stage16(const void* g, void* l) {
  __builtin_amdgcn_global_load_lds(
      (const __attribute__((address_space(1))) void*)g,
      (__attribute__((address_space(3))) void*)l, 16, 0, 0);
}

#define LOADA(BUF, QM)                                                         \
  _Pragma("unroll") for (int t = 0; t < 4; ++t) {                              \
    af[t][0] = *(const short8*)(aRd0 + (BUF)*32768 + (QM)*16384 + t*2048);     \
    af[t][1] = *(const short8*)(aRd1 + (BUF)*32768 + (QM)*16384 + t*2048);     \
  }

#define LOADB(BUF, QN)                                                         \
  _Pragma("unroll") for (int j = 0; j < 2; ++j) {                              \
    bf[j][0] = *(const short8*)(bRd0 + (BUF)*32768 + (QN)*16384 + j*2048);     \
    bf[j][1] = *(const short8*)(bRd1 + (BUF)*32768 + (QN)*16384 + j*2048);     \
  }

#define MFMAQ(QM, QN)                                                          \
  _Pragma("unroll") for (int t = 0; t < 4; ++t)                                \
  _Pragma("unroll") for (int j = 0; j < 2; ++j)                                \
    acc[QM][QN][t][j] = __builtin_amdgcn_mfma_f32_16x16x32_bf16(               \
        af[t][0], bf[j][0], acc[QM][QN][t][j], 0, 0, 0);                       \
  _Pragma("unroll") for (int t = 0; t < 4; ++t)                                \
  _Pragma("unroll") for (int j = 0; j < 2; ++j)                                \
    acc[QM][QN][t][j] = __builtin_amdgcn_mfma_f32_16x16x32_bf16(               \
        af[t][1], bf[j][1], acc[QM][QN][t][j], 0, 0, 0);

#define SYNC_MID()                                      \
  __builtin_amdgcn_sched_barrier(0);                    \
  __builtin_amdgcn_s_barrier();                         \
  asm volatile("s_waitcnt lgkmcnt(0)" ::: "memory");    \
  __builtin_amdgcn_sched_barrier(0);                    \
  __builtin_amdgcn_s_setprio(1)

#define SYNC_END()                                      \
  __builtin_amdgcn_s_setprio(0);                        \
  __builtin_amdgcn_sched_barrier(0);                    \
  __builtin_amdgcn_s_barrier();                         \
  __builtin_amdgcn_sched_barrier(0)

#define SYNC_END_VM()                                   \
  __builtin_amdgcn_s_setprio(0);                        \
  __builtin_amdgcn_sched_barrier(0);                    \
  asm volatile("s_waitcnt vmcnt(4)" ::: "memory");      \
  __builtin_amdgcn_s_barrier();                         \
  __builtin_amdgcn_sched_barrier(0)

__global__ __launch_bounds__(512, 2) void gemm_bt_kernel(
    const unsigned short* __restrict__ A,   // x bf16 [M, K]
    const unsigned short* __restrict__ B,   // W_eff bf16 [N, K]
    float* __restrict__ C, int M) {
  __shared__ __align__(16) char lds[131072];

  const int tid  = threadIdx.x;
  const int lane = tid & 63;
  const int wave = tid >> 6;      // 0..7
  const int wm   = wave >> 2;     // 0..1 (128 rows each)
  const int wn   = wave & 3;      // 0..3 (64 cols each)
  const int lrow = lane & 15;
  const int lq   = lane >> 4;     // 0..3
  const int r7   = lrow & 7;

  // XCD-bijective block swizzle (gridDim.x % 8 == 0 here: 512 blocks).
  const int bid = blockIdx.x;
  const int cpx = gridDim.x >> 3;
  const int swz = (bid & 7) * cpx + (bid >> 3);
  const int m0 = (swz >> 4) << 8;           // 16 n-tiles (D_DIM/256)
  const int n0 = (swz & 15) << 8;

  // ---- staging source bases (per thread) ----
  // thread covers LDS row L = L0 + (tid>>3), slot tid&7; source kgroup is
  // (tid&7) ^ ((tid>>3)&7) (inverse of the read-side XOR swizzle).
  const int rr8  = tid >> 3;                               // 0..63
  const int kgsw = (tid & 7) ^ (rr8 & 7);
  // A: global row = rr8 | swap67(L0): issue row bases {0,128,64,192}.
  const char* aSrc = (const char*)A + ((size_t)(m0 + rr8) << 13) + (kgsw << 4);
  // B: global row = (rr8&31) | ((rr8&32)<<1) + base, bases {0,128}/{32,160}.
  const int nrow = (rr8 & 31) | ((rr8 & 32) << 1);
  const char* bSrc = (const char*)B + ((size_t)(n0 + nrow) << 13) + (kgsw << 4);
  char* ldsW = lds + wave * 1024;           // wave-uniform dest base

  // ---- fragment read bases (per lane) ----
  const char* aRd0 = lds + wm * 8192 + lrow * 128 + ((lq ^ r7) << 4);
  const char* aRd1 = lds + wm * 8192 + lrow * 128 + (((4 | lq) ^ r7) << 4);
  const char* bRd0 = lds + 65536 + wn * 4096 + lrow * 128 + ((lq ^ r7) << 4);
  const char* bRd1 = lds + 65536 + wn * 4096 + lrow * 128 + (((4 | lq) ^ r7) << 4);

  short8 af[4][2], bf[2][2];
  floatx4 acc[2][2][4][2] = {};   // [qm][qn][t][j]

  // ---- prologue: tile0 (all 4 halves) -> buf0, A0(1)+B1(1) -> buf1 ----
  stage16(aSrc,                     ldsW + 0);        // A0(0) rows 0-63
  stage16(aSrc + (128 << 13),       ldsW + 8192);     // A0(0) rows 128-191
  stage16(aSrc + (64 << 13),        ldsW + 16384);    // A1(0) rows 64-127
  stage16(aSrc + (192 << 13),       ldsW + 24576);    // A1(0) rows 192-255
  stage16(bSrc,                     ldsW + 65536);    // B0(0)
  stage16(bSrc + (128 << 13),       ldsW + 73728);
  stage16(bSrc + (32 << 13),        ldsW + 81920);    // B1(0)
  stage16(bSrc + (160 << 13),       ldsW + 90112);
  stage16(aSrc + 128,               ldsW + 32768);    // A0(1), ktile=1
  stage16(aSrc + (128 << 13) + 128, ldsW + 40960);
  stage16(bSrc + (32 << 13) + 128,  ldsW + 114688);   // B1(1)
  stage16(bSrc + (160 << 13) + 128, ldsW + 122880);
  asm volatile("s_waitcnt vmcnt(4)" ::: "memory");    // tile0 landed
  __builtin_amdgcn_s_barrier();
  __builtin_amdgcn_sched_barrier(0);

  int kb = 0;                                // f*256 bytes (2 tiles/frame)
#pragma unroll 1
  for (int f = 0; f < 32; ++f) {             // 64 K-tiles, 2 per frame
    const int k1 = (kb + 128) & 8191;        // ktile 2f+1 byte offset
    const int k2 = (kb + 256) & 8191;        // ktile 2f+2 (wraps at tail)
    const int k3 = (kb + 384) & 8191;        // ktile 2f+3 (wraps at tail)

    // P1: tile 2f c1=(0,0) from buf0; stage A1(2f+1)->buf1
    LOADA(0, 0) LOADB(0, 0)
    stage16(aSrc + (64 << 13) + k1,  ldsW + 49152);
    stage16(aSrc + (192 << 13) + k1, ldsW + 57344);
    SYNC_MID();
    MFMAQ(0, 0)
    SYNC_END();

    // P2: c2=(0,1) (A reused); stage B0(2f+1)->buf1
    LOADB(0, 1)
    stage16(bSrc + k1,               ldsW + 98304);
    stage16(bSrc + (128 << 13) + k1, ldsW + 106496);
    SYNC_MID();
    MFMAQ(0, 1)
    SYNC_END();

    // P3: c3=(1,1) (B reused); stage A0(2f+2)->buf0 (A0 retired after P1)
    LOADA(0, 1)
    stage16(aSrc + k2,               ldsW + 0);
    stage16(aSrc + (128 << 13) + k2, ldsW + 8192);
    SYNC_MID();
    MFMAQ(1, 1)
    SYNC_END();

    // P4: c4=(1,0) (A reused); stage B1(2f+2)->buf0 (B1 retired after P2)
    LOADB(0, 0)
    stage16(bSrc + (32 << 13) + k2,  ldsW + 81920);
    stage16(bSrc + (160 << 13) + k2, ldsW + 90112);
    SYNC_MID();
    MFMAQ(1, 0)
    SYNC_END_VM();   // vmcnt(4): everything except P3/P4 stages landed

    // P5: tile 2f+1 c1=(0,0) from buf1; stage A1(2f+2)->buf0
    LOADA(1, 0) LOADB(1, 0)
    stage16(aSrc + (64 << 13) + k2,  ldsW + 16384);
    stage16(aSrc + (192 << 13) + k2, ldsW + 24576);
    SYNC_MID();
    MFMAQ(0, 0)
    SYNC_END();

    // P6: c2=(0,1); stage B0(2f+2)->buf0
    LOADB(1, 1)
    stage16(bSrc + k2,               ldsW + 65536);
    stage16(bSrc + (128 << 13) + k2, ldsW + 73728);
    SYNC_MID();
    MFMAQ(0, 1)
    SYNC_END();

    // P7: c3=(1,1); stage A0(2f+3)->buf1
    LOADA(1, 1)
    stage16(aSrc + k3,               ldsW + 32768);
    stage16(aSrc + (128 << 13) + k3, ldsW + 40960);
    SYNC_MID();
    MFMAQ(1, 1)
    SYNC_END();

    // P8: c4=(1,0); stage B1(2f+3)->buf1
    LOADB(1, 0)
    stage16(bSrc + (32 << 13) + k3,  ldsW + 114688);
    stage16(bSrc + (160 << 13) + k3, ldsW + 122880);
    SYNC_MID();
    MFMAQ(1, 0)
    SYNC_END_VM();

    kb += 256;
  }

  // ---- epilogue: D row=(lq*4+rr), col=lrow within each 16x16 fragment ----
#pragma unroll
  for (int qm = 0; qm < 2; ++qm)
#pragma unroll
    for (int t = 0; t < 4; ++t)
#pragma unroll
      for (int rr = 0; rr < 4; ++rr) {
        float* cp = C +
            (size_t)(m0 + wm * 128 + qm * 64 + t * 16 + lq * 4 + rr) * D_DIM +
            n0 + wn * 64 + lrow;
#pragma unroll
        for (int qn = 0; qn < 2; ++qn)
#pragma unroll
          for (int j = 0; j < 2; ++j)
            cp[qn * 32 + j * 16] = acc[qm][qn][t][j][rr];
      }
}

extern "C" void kernel_launch(void* const* d_in, const int* in_sizes, int n_in,
                              void* d_out, int out_size, void* d_ws, size_t ws_size,
                              hipStream_t stream) {
  const float* x     = (const float*)d_in[0];  // [M, 4096], M = 8192
  const float* W     = (const float*)d_in[1];  // [4096, 4096]
  const float* lA    = (const float*)d_in[2];  // [16, 4096]
  const float* lB    = (const float*)d_in[3];  // [4096, 16]
  const float* sigma = (const float*)d_in[4];  // [16]
  float* out = (float*)d_out;

  const int M = in_sizes[0] / D_DIM;           // 8192
  // Workspace layout: x_bf16 (M*4096*2 = 64 MB) then W_eff bf16 (32 MB).
  unsigned int* xb = (unsigned int*)d_ws;
  unsigned int* wb = (unsigned int*)((char*)d_ws + (size_t)M * D_DIM * 2);

  const int n8 = in_sizes[0] / 8;              // x octets
  convert_x_kernel<<<(n8 + 255) / 256, 256, 0, stream>>>(x, xb, n8);

  const int wquads = (D_DIM * D_DIM) / 4;      // 4,194,304
  build_weff_kernel<<<wquads / 256, 256, 0, stream>>>(W, lA, lB, sigma, wb);

  const int nblocks = (M / 256) * (D_DIM / 256);   // 32*16 = 512
  gemm_bt_kernel<<<nblocks, 512, 0, stream>>>(
      (const unsigned short*)xb, (const unsigned short*)wb, out, M);
}